// Round 3
// baseline (1309.841 us; speedup 1.0000x reference)
//
#include <hip/hip_runtime.h>
#include <hip/hip_bf16.h>

// Problem dims (fixed by setup_inputs)
#define S   2048
#define D   1024
#define DFF 4096
#define NH  16
#define HD  64

typedef unsigned short u16;

__device__ __forceinline__ float bu2f(u16 u) {
    union { unsigned int i; float f; } x; x.i = ((unsigned int)u) << 16; return x.f;
}
__device__ __forceinline__ u16 f2bu(float f) {
    __hip_bfloat16 h = __float2bfloat16(f);
    return *(u16*)&h;
}
__device__ __forceinline__ float4 ld4(const float* p) { return *(const float4*)p; }
__device__ __forceinline__ float4 ld4(const u16* p) {
    ushort4 u = *(const ushort4*)p;
    return make_float4(bu2f(u.x), bu2f(u.y), bu2f(u.z), bu2f(u.w));
}

// ---------------- LayerNorm: one block per row, D=1024, 256 threads ----------
__global__ __launch_bounds__(256, 4)
void ln_kernel(const float* __restrict__ in, const float* __restrict__ ga,
               const float* __restrict__ gb, float* __restrict__ out)
{
    const int row = blockIdx.x;
    const int t = threadIdx.x;
    const float* x = in + (size_t)row * D;
    float v[4];
    float s = 0.f, ss = 0.f;
#pragma unroll
    for (int j = 0; j < 4; j++) {
        float val = x[t + 256 * j];
        v[j] = val; s += val; ss = fmaf(val, val, ss);
    }
#pragma unroll
    for (int off = 32; off >= 1; off >>= 1) {
        s  += __shfl_down(s,  off, 64);
        ss += __shfl_down(ss, off, 64);
    }
    __shared__ float red[10];
    const int wave = t >> 6, lane = t & 63;
    if (lane == 0) { red[wave] = s; red[4 + wave] = ss; }
    __syncthreads();
    if (t == 0) {
        float S1 = red[0] + red[1] + red[2] + red[3];
        float S2 = red[4] + red[5] + red[6] + red[7];
        float mu = S1 / (float)D;
        float var = (S2 - (float)D * mu * mu) / (float)(D - 1);  // ddof=1
        float sig = sqrtf(fmaxf(var, 0.f)) + 1e-6f;              // eps added to sigma
        red[8] = mu; red[9] = 1.f / sig;
    }
    __syncthreads();
    const float mu = red[8], rs = red[9];
#pragma unroll
    for (int j = 0; j < 4; j++) {
        int c = t + 256 * j;
        out[(size_t)row * D + c] = (v[j] - mu) * rs * ga[c] + gb[c];
    }
}

// ---------------- Generic GEMM: C[m,n] = sum_k A[m,k] * B[n,k] (+bias/res) ---
// A [M,K] row-major (fp32 or bf16), B fp32 [N,K] row-major (weights [out,in]).
// 64x64 tile / block (256 thr), 4x4 per thread, BK=32, LDS tiles transposed.
template <typename TA, bool RELU, bool TROUT, bool OUTBF>
__global__ __launch_bounds__(256, 4)
void gemm_kernel(const TA* __restrict__ A, const float* __restrict__ B,
                 const float* __restrict__ bias, const float* __restrict__ res,
                 void* __restrict__ Cout, int M, int N, int K)
{
    __shared__ float As[32][68];   // [k][m]
    __shared__ float Bs[32][68];   // [k][n]
    const int t  = threadIdx.x;
    const int m0 = blockIdx.y * 64, n0 = blockIdx.x * 64;
    const int tx = t & 15, ty = t >> 4;
    const int lr = t >> 3, lc = (t & 7) * 4;
    float acc[4][4] = {};

    const TA*    Ap = A + (size_t)(m0 + lr) * K + lc;
    const float* Bp = B + (size_t)(n0 + lr) * K + lc;

    for (int k0 = 0; k0 < K; k0 += 32) {
        float4 a0 = ld4(Ap + k0);
        float4 a1 = ld4(Ap + (size_t)32 * K + k0);
        float4 b0 = ld4(Bp + k0);
        float4 b1 = ld4(Bp + (size_t)32 * K + k0);
        __syncthreads();
        As[lc + 0][lr] = a0.x; As[lc + 1][lr] = a0.y;
        As[lc + 2][lr] = a0.z; As[lc + 3][lr] = a0.w;
        As[lc + 0][lr + 32] = a1.x; As[lc + 1][lr + 32] = a1.y;
        As[lc + 2][lr + 32] = a1.z; As[lc + 3][lr + 32] = a1.w;
        Bs[lc + 0][lr] = b0.x; Bs[lc + 1][lr] = b0.y;
        Bs[lc + 2][lr] = b0.z; Bs[lc + 3][lr] = b0.w;
        Bs[lc + 0][lr + 32] = b1.x; Bs[lc + 1][lr + 32] = b1.y;
        Bs[lc + 2][lr + 32] = b1.z; Bs[lc + 3][lr + 32] = b1.w;
        __syncthreads();
#pragma unroll
        for (int kk = 0; kk < 32; kk++) {
            float4 av = *(const float4*)&As[kk][ty * 4];
            float4 bv = *(const float4*)&Bs[kk][tx * 4];
            float a[4] = {av.x, av.y, av.z, av.w};
            float b[4] = {bv.x, bv.y, bv.z, bv.w};
#pragma unroll
            for (int i = 0; i < 4; i++)
#pragma unroll
                for (int j = 0; j < 4; j++)
                    acc[i][j] = fmaf(a[i], b[j], acc[i][j]);
        }
    }

    if (TROUT) {
        // store C^T (fp32): out[n*M + m]  (K -> Kt[h*64+d][s]); bias fused
        float* C = (float*)Cout;
#pragma unroll
        for (int j = 0; j < 4; j++) {
            int n = n0 + tx * 4 + j;
            float bn = bias[n];
            float4 st = make_float4(acc[0][j] + bn, acc[1][j] + bn,
                                    acc[2][j] + bn, acc[3][j] + bn);
            *(float4*)(C + (size_t)n * M + m0 + ty * 4) = st;
        }
    } else {
#pragma unroll
        for (int i = 0; i < 4; i++) {
            int m = m0 + ty * 4 + i;
            int n = n0 + tx * 4;
            float4 bv4 = *(const float4*)(bias + n);
            float4 cv;
            cv.x = acc[i][0] + bv4.x;
            cv.y = acc[i][1] + bv4.y;
            cv.z = acc[i][2] + bv4.z;
            cv.w = acc[i][3] + bv4.w;
            if (RELU) {
                cv.x = fmaxf(cv.x, 0.f); cv.y = fmaxf(cv.y, 0.f);
                cv.z = fmaxf(cv.z, 0.f); cv.w = fmaxf(cv.w, 0.f);
            }
            if (res) {
                float4 rf = *(const float4*)(res + (size_t)m * N + n);
                cv.x += rf.x; cv.y += rf.y; cv.z += rf.z; cv.w += rf.w;
            }
            if (OUTBF) {
                ushort4 st;
                st.x = f2bu(cv.x); st.y = f2bu(cv.y);
                st.z = f2bu(cv.z); st.w = f2bu(cv.w);
                *(ushort4*)((u16*)Cout + (size_t)m * N + n) = st;
            } else {
                *(float4*)((float*)Cout + (size_t)m * N + n) = cv;
            }
        }
    }
}

// ---------------- Fused sparse attention: scores -> entmax1.5 -> P*V ---------
// grid = NH * (S/8) blocks (h = bid>>8), 256 threads, 8 query rows per block.
// q:  [S, D] fp32   (row s, cols h*64+d)
// kT: [NH*64][S]    fp32 (transposed K for coalesced score reads)
// v:  [S, D] fp32
// entmax1.5: solve sum relu(x - tau)^2 = 1 by Newton on convex g (12 iters).
__global__ __launch_bounds__(256, 2)
void attn_kernel(const float* __restrict__ qbuf, const float* __restrict__ kT,
                 const float* __restrict__ vbuf, const int* __restrict__ mask,
                 float* __restrict__ att)
{
    __shared__ float sc[8 * 2048];   // 64 KB: scores/P; front reused for q-tile & partials
    const int h  = blockIdx.x >> 8;
    const int qb = blockIdx.x & 255;
    const int q0 = qb * 8;
    const int t  = threadIdx.x;

    // stage q rows into front of sc (dead once the d-loop finishes)
    float* qs = sc;
    {
        int r = t >> 6, d = t & 63;
        qs[r * 64 + d]       = qbuf[(size_t)(q0 + r) * D + h * HD + d];
        qs[(r + 4) * 64 + d] = qbuf[(size_t)(q0 + r + 4) * D + h * HD + d];
    }
    __syncthreads();

    // ---- score phase: thread t owns k = 4t..4t+3 and 4t+1024..4t+1027 ----
    float acc[8][8];
#pragma unroll
    for (int r = 0; r < 8; r++)
#pragma unroll
        for (int j = 0; j < 8; j++) acc[r][j] = 0.f;

    const float* kb = kT + (size_t)h * HD * S;
#pragma unroll 4
    for (int d = 0; d < HD; d++) {
        float4 k0 = *(const float4*)(kb + (size_t)d * S + 4 * t);
        float4 k1 = *(const float4*)(kb + (size_t)d * S + 4 * t + 1024);
#pragma unroll
        for (int r = 0; r < 8; r++) {
            float qd = qs[r * 64 + d];
            acc[r][0] = fmaf(qd, k0.x, acc[r][0]);
            acc[r][1] = fmaf(qd, k0.y, acc[r][1]);
            acc[r][2] = fmaf(qd, k0.z, acc[r][2]);
            acc[r][3] = fmaf(qd, k0.w, acc[r][3]);
            acc[r][4] = fmaf(qd, k1.x, acc[r][4]);
            acc[r][5] = fmaf(qd, k1.y, acc[r][5]);
            acc[r][6] = fmaf(qd, k1.z, acc[r][6]);
            acc[r][7] = fmaf(qd, k1.w, acc[r][7]);
        }
    }
    const int4 mk0 = *(const int4*)(mask + 4 * t);
    const int4 mk1 = *(const int4*)(mask + 4 * t + 1024);
    __syncthreads();   // all threads done reading qs; sc may be overwritten

    // scale = (1/sqrt(64)) * (1/2 from entmax) = 0.0625 ; masked -> -1e9/2
#pragma unroll
    for (int r = 0; r < 8; r++) {
        float4 w0, w1;
        w0.x = mk0.x ? acc[r][0] * 0.0625f : -5e8f;
        w0.y = mk0.y ? acc[r][1] * 0.0625f : -5e8f;
        w0.z = mk0.z ? acc[r][2] * 0.0625f : -5e8f;
        w0.w = mk0.w ? acc[r][3] * 0.0625f : -5e8f;
        w1.x = mk1.x ? acc[r][4] * 0.0625f : -5e8f;
        w1.y = mk1.y ? acc[r][5] * 0.0625f : -5e8f;
        w1.z = mk1.z ? acc[r][6] * 0.0625f : -5e8f;
        w1.w = mk1.w ? acc[r][7] * 0.0625f : -5e8f;
        *(float4*)&sc[r * 2048 + 4 * t]        = w0;
        *(float4*)&sc[r * 2048 + 4 * t + 1024] = w1;
    }
    __syncthreads();

    // ---- entmax1.5 via Newton: 32 lanes per row, values cached in regs ----
    {
        const int lane = t & 63;
        const int r    = (t >> 6) * 2 + (lane >> 5);
        const int l32  = lane & 31;
        float xv[64];
#pragma unroll
        for (int j = 0; j < 64; j++) xv[j] = sc[r * 2048 + l32 + 32 * j];
        float mx = -1e30f;
#pragma unroll
        for (int j = 0; j < 64; j++) mx = fmaxf(mx, xv[j]);
#pragma unroll
        for (int off = 16; off >= 1; off >>= 1) mx = fmaxf(mx, __shfl_xor(mx, off, 32));
        float tau = mx - 1.0f;   // g(tau0) >= 1, g convex decreasing -> monotone Newton
        for (int it = 0; it < 12; it++) {
            float s1 = 0.f, s2 = 0.f;
#pragma unroll
            for (int j = 0; j < 64; j++) {
                float dp = fmaxf(xv[j] - tau, 0.f);
                s1 += dp; s2 = fmaf(dp, dp, s2);
            }
#pragma unroll
            for (int off = 16; off >= 1; off >>= 1) {
                s1 += __shfl_xor(s1, off, 32);
                s2 += __shfl_xor(s2, off, 32);
            }
            tau += (s2 - 1.0f) / (2.0f * s1);   // s1 >= 1 whenever g >= 1
        }
#pragma unroll
        for (int j = 0; j < 64; j++) {
            float dp = fmaxf(xv[j] - tau, 0.f);
            sc[r * 2048 + l32 + 32 * j] = dp * dp;   // P in place
        }
    }
    __syncthreads();

    // ---- PV: thread (d = t&63, g = t>>6); P broadcast-read as float4 ----
    {
        const int d = t & 63, g = t >> 6;
        float o[8] = {};
        const float* vb = vbuf + (size_t)h * HD + d;
        for (int kq = 0; kq < 128; kq++) {
            int k = g * 512 + kq * 4;
            float v0 = vb[(size_t)(k + 0) * D];
            float v1 = vb[(size_t)(k + 1) * D];
            float v2 = vb[(size_t)(k + 2) * D];
            float v3 = vb[(size_t)(k + 3) * D];
#pragma unroll
            for (int r = 0; r < 8; r++) {
                float4 p = *(const float4*)&sc[r * 2048 + k];
                o[r] = fmaf(p.x, v0, o[r]);
                o[r] = fmaf(p.y, v1, o[r]);
                o[r] = fmaf(p.z, v2, o[r]);
                o[r] = fmaf(p.w, v3, o[r]);
            }
        }
        __syncthreads();   // all P reads done; reuse sc front for partials
#pragma unroll
        for (int r = 0; r < 8; r++) sc[(g * 8 + r) * 64 + d] = o[r];
    }
    __syncthreads();
    for (int i = t; i < 512; i += 256) {
        int r = i >> 6, d = i & 63;
        float sum = sc[(0 * 8 + r) * 64 + d] + sc[(1 * 8 + r) * 64 + d]
                  + sc[(2 * 8 + r) * 64 + d] + sc[(3 * 8 + r) * 64 + d];
        att[(size_t)(q0 + r) * D + h * HD + d] = sum;
    }
}

// ---------------- host side ---------------------------------------------------
extern "C" void kernel_launch(void* const* d_in, const int* in_sizes, int n_in,
                              void* d_out, int out_size, void* d_ws, size_t ws_size,
                              hipStream_t stream)
{
    const float* inp  = (const float*)d_in[0];
    const int*   mask = (const int*)d_in[1];
    const float* wq   = (const float*)d_in[2];
    const float* bq   = (const float*)d_in[3];
    const float* wk   = (const float*)d_in[4];
    const float* bk   = (const float*)d_in[5];
    const float* wv   = (const float*)d_in[6];
    const float* bv   = (const float*)d_in[7];
    const float* wo   = (const float*)d_in[8];
    const float* bo   = (const float*)d_in[9];
    const float* ln1a = (const float*)d_in[10];
    const float* ln1b = (const float*)d_in[11];
    const float* w1   = (const float*)d_in[12];
    const float* b1   = (const float*)d_in[13];
    const float* w2   = (const float*)d_in[14];
    const float* b2   = (const float*)d_in[15];
    const float* ln2a = (const float*)d_in[16];
    const float* ln2b = (const float*)d_in[17];

    const size_t MB = 1u << 20;
    char* w = (char*)d_ws;
    // Liveness-overlaid layout, total footprint 32 MB (all fp32 except hb bf16):
    //   [0,8):   x1 -> att -> x2
    //   [8,16):  q  -> y (q dead once attn done; y live to step 7)
    //   [16,24): kT -\
    //   [24,32): v   -> dead after attn -> hb bf16 [16,32)
    float* x1   = (float*)(w + 0 * MB);
    float* qbuf = (float*)(w + 8 * MB);
    float* kTb  = (float*)(w + 16 * MB);
    float* vbuf = (float*)(w + 24 * MB);
    float* att  = x1;
    float* x2   = x1;
    float* y    = (float*)(w + 8 * MB);
    u16*   hb   = (u16*)(w + 16 * MB);
    float* outF = (float*)d_out;

    // 1. LN1
    ln_kernel<<<S, 256, 0, stream>>>(inp, ln1a, ln1b, x1);
    // 2. Q,K(->transposed),V projections
    gemm_kernel<float, false, false, false><<<dim3(D / 64, S / 64), 256, 0, stream>>>(
        x1, wq, bq, nullptr, qbuf, S, D, D);
    gemm_kernel<float, false, true, false><<<dim3(D / 64, S / 64), 256, 0, stream>>>(
        x1, wk, bk, nullptr, kTb, S, D, D);
    gemm_kernel<float, false, false, false><<<dim3(D / 64, S / 64), 256, 0, stream>>>(
        x1, wv, bv, nullptr, vbuf, S, D, D);
    // 3. fused entmax attention (overwrites x1 slot)
    attn_kernel<<<NH * (S / 8), 256, 0, stream>>>(qbuf, kTb, vbuf, mask, att);
    // 4. output projection + residual(inputs) -> y (q slot dead)
    gemm_kernel<float, false, false, false><<<dim3(D / 64, S / 64), 256, 0, stream>>>(
        att, wo, bo, inp, y, S, D, D);
    // 5. LN2 -> x2 (att dead)
    ln_kernel<<<S, 256, 0, stream>>>(y, ln2a, ln2b, x2);
    // 6. FFN1 (+ReLU) -> bf16 hidden (kT/v dead)
    gemm_kernel<float, true, false, true><<<dim3(DFF / 64, S / 64), 256, 0, stream>>>(
        x2, w1, b1, nullptr, hb, S, DFF, D);
    // 7. FFN2 + residual(y) -> fp32 out
    gemm_kernel<u16, false, false, false><<<dim3(D / 64, S / 64), 256, 0, stream>>>(
        hb, w2, b2, y, outF, S, D, DFF);
}

// Round 4
// 768.930 us; speedup vs baseline: 1.7035x; 1.7035x over previous
//
#include <hip/hip_runtime.h>
#include <hip/hip_bf16.h>

// Problem dims (fixed by setup_inputs)
#define S   2048
#define D   1024
#define DFF 4096
#define NH  16
#define HD  64

typedef unsigned short u16;
typedef unsigned int   u32;
typedef __attribute__((ext_vector_type(8))) short short8;   // 8 bf16 (4 VGPRs)
typedef __attribute__((ext_vector_type(4))) float floatx4;  // MFMA C/D

__device__ __forceinline__ float bu2f(u16 u) {
    union { u32 i; float f; } x; x.i = ((u32)u) << 16; return x.f;
}
__device__ __forceinline__ u16 f2bu(float f) {
    __hip_bfloat16 h = __float2bfloat16(f);
    return *(u16*)&h;
}
__device__ __forceinline__ float ldf(const float* p) { return *p; }
__device__ __forceinline__ float ldf(const u16* p)   { return bu2f(*p); }

// async global->LDS, 16B per lane, lands at ldsbase + lane*16
__device__ __forceinline__ void async16(const void* g, void* l) {
    __builtin_amdgcn_global_load_lds(
        (const __attribute__((address_space(1))) u32*)g,
        (__attribute__((address_space(3))) u32*)l, 16, 0, 0);
}

// ---------------- fp32 -> bf16 bulk convert (weights) ------------------------
__global__ __launch_bounds__(256)
void cvt_kernel(const float* __restrict__ in, u16* __restrict__ out, int n4)
{
    int i = blockIdx.x * 256 + threadIdx.x;
    if (i < n4) {
        float4 v = ((const float4*)in)[i];
        ushort4 s;
        s.x = f2bu(v.x); s.y = f2bu(v.y); s.z = f2bu(v.z); s.w = f2bu(v.w);
        ((ushort4*)out)[i] = s;
    }
}

// ---------------- LayerNorm: one block per row, D=1024, 256 threads ----------
// out bf16 always.
template <typename T>
__global__ __launch_bounds__(256, 4)
void ln_kernel(const T* __restrict__ in, const float* __restrict__ ga,
               const float* __restrict__ gb, u16* __restrict__ out)
{
    const int row = blockIdx.x;
    const int t = threadIdx.x;
    const T* x = in + (size_t)row * D;
    float v[4];
    float s = 0.f, ss = 0.f;
#pragma unroll
    for (int j = 0; j < 4; j++) {
        float val = ldf(x + t + 256 * j);
        v[j] = val; s += val; ss = fmaf(val, val, ss);
    }
#pragma unroll
    for (int off = 32; off >= 1; off >>= 1) {
        s  += __shfl_down(s,  off, 64);
        ss += __shfl_down(ss, off, 64);
    }
    __shared__ float red[10];
    const int wave = t >> 6, lane = t & 63;
    if (lane == 0) { red[wave] = s; red[4 + wave] = ss; }
    __syncthreads();
    if (t == 0) {
        float S1 = red[0] + red[1] + red[2] + red[3];
        float S2 = red[4] + red[5] + red[6] + red[7];
        float mu = S1 / (float)D;
        float var = (S2 - (float)D * mu * mu) / (float)(D - 1);  // ddof=1
        float sig = sqrtf(fmaxf(var, 0.f)) + 1e-6f;              // eps on sigma
        red[8] = mu; red[9] = 1.f / sig;
    }
    __syncthreads();
    const float mu = red[8], rs = red[9];
#pragma unroll
    for (int j = 0; j < 4; j++) {
        int c = t + 256 * j;
        out[(size_t)row * D + c] = f2bu((v[j] - mu) * rs * ga[c] + gb[c]);
    }
}

// ---------------- MFMA GEMM: C[m,n] = sum_k A[m,k]*B[n,k] (+bias/relu/res) ---
// A,B bf16 row-major [M,K]/[N,K]. 128x128 tile, 256 thr (4 waves, each 64x64 of
// 4x4 16x16x32 MFMAs), BK=32, global_load_lds width-16 staging, XOR-swizzled
// LDS 16B slots (slot = kq ^ ((row>>1)&3)) -> 2-way bank aliasing (free).
// OMODE: 0 fp32 [M,N] · 1 bf16 [M,N] · 3 bf16 transposed [N,M]
// RES:   0 none · 1 fp32 · 2 bf16
template <int OMODE, bool RELU, int RES>
__global__ __launch_bounds__(256, 2)
void gemm_mfma(const u16* __restrict__ A, const u16* __restrict__ B,
               const float* __restrict__ bias, const void* __restrict__ res,
               void* __restrict__ Cout, int M, int N, int K)
{
    __shared__ u16 As[128 * 32];
    __shared__ u16 Bs[128 * 32];
    const int t = threadIdx.x;
    const int w = t >> 6, l = t & 63;
    const int m0 = blockIdx.y * 128, n0 = blockIdx.x * 128;
    const int qk = l >> 4, col = l & 15;
    const int wm = (w & 1) * 64, wn = (w >> 1) * 64;

    // staging coords: each wave stages rows [w*16, w*16+16) and +64 (A and B)
    const int sr  = l >> 2;                    // row within 16-row segment
    const int sq  = l & 3;                     // stored 16B slot
    const int row = w * 16 + sr;
    const int gq  = sq ^ ((row >> 1) & 3);     // global k-quad fetched
    const u16* Ap = A + (size_t)(m0 + row) * K + gq * 8;
    const u16* Bp = B + (size_t)(n0 + row) * K + gq * 8;
    u16* AsW = As + w * 16 * 32;               // wave-uniform LDS bases
    u16* BsW = Bs + w * 16 * 32;

    // fragment read bases: global quad qk of row mloc sits at slot qk^((mloc>>1)&3)
    const int mloc = wm + col, nloc = wn + col;
    const u16* aBase = As + mloc * 32 + (qk ^ ((mloc >> 1) & 3)) * 8;
    const u16* bBase = Bs + nloc * 32 + (qk ^ ((nloc >> 1) & 3)) * 8;

    floatx4 acc[4][4];
#pragma unroll
    for (int i = 0; i < 4; i++)
#pragma unroll
        for (int j = 0; j < 4; j++)
            acc[i][j] = (floatx4)0.f;

    for (int k0 = 0; k0 < K; k0 += 32) {
        __syncthreads();                       // prev-iter LDS reads done
        async16(Ap,                 AsW);
        async16(Ap + (size_t)64 * K, AsW + 64 * 32);
        async16(Bp,                 BsW);
        async16(Bp + (size_t)64 * K, BsW + 64 * 32);
        Ap += 32; Bp += 32;
        __syncthreads();                       // staging visible to all waves
        short8 a[4], b[4];
#pragma unroll
        for (int i = 0; i < 4; i++) a[i] = *(const short8*)(aBase + i * 16 * 32);
#pragma unroll
        for (int j = 0; j < 4; j++) b[j] = *(const short8*)(bBase + j * 16 * 32);
#pragma unroll
        for (int i = 0; i < 4; i++)
#pragma unroll
            for (int j = 0; j < 4; j++)
                acc[i][j] = __builtin_amdgcn_mfma_f32_16x16x32_bf16(
                    a[i], b[j], acc[i][j], 0, 0, 0);
    }

    // epilogue: C/D layout col=lane&15, row=qk*4+reg  [m89/m91]
#pragma unroll
    for (int j = 0; j < 4; j++) {
        const int n = n0 + wn + j * 16 + col;
        const float bn = bias[n];
#pragma unroll
        for (int i = 0; i < 4; i++) {
#pragma unroll
            for (int r = 0; r < 4; r++) {
                const int m = m0 + wm + i * 16 + qk * 4 + r;
                float v = acc[i][j][r] + bn;
                if (RELU) v = fmaxf(v, 0.f);
                if (RES == 1) v += ((const float*)res)[(size_t)m * N + n];
                if (RES == 2) v += bu2f(((const u16*)res)[(size_t)m * N + n]);
                if (OMODE == 0) ((float*)Cout)[(size_t)m * N + n] = v;
                if (OMODE == 1) ((u16*)Cout)[(size_t)m * N + n] = f2bu(v);
                if (OMODE == 3) ((u16*)Cout)[(size_t)n * M + m] = f2bu(v);
            }
        }
    }
}

// ---------------- Fused sparse attention: scores -> entmax1.5 -> P*V ---------
// grid = NH * (S/8) blocks, 256 threads, 8 query rows per block. q/kT/v bf16.
__global__ __launch_bounds__(256, 2)
void attn_kernel(const u16* __restrict__ qbuf, const u16* __restrict__ kT,
                 const u16* __restrict__ vbuf, const int* __restrict__ mask,
                 u16* __restrict__ att)
{
    __shared__ float sc[8 * 2048];   // 64 KB: scores/P; front reused q-tile & partials
    const int h  = blockIdx.x >> 8;
    const int qb = blockIdx.x & 255;
    const int q0 = qb * 8;
    const int t  = threadIdx.x;

    float* qs = sc;
    {
        int r = t >> 6, d = t & 63;
        qs[r * 64 + d]       = bu2f(qbuf[(size_t)(q0 + r) * D + h * HD + d]);
        qs[(r + 4) * 64 + d] = bu2f(qbuf[(size_t)(q0 + r + 4) * D + h * HD + d]);
    }
    __syncthreads();

    float acc[8][8];
#pragma unroll
    for (int r = 0; r < 8; r++)
#pragma unroll
        for (int j = 0; j < 8; j++) acc[r][j] = 0.f;

    const u16* kb = kT + (size_t)h * HD * S;
#pragma unroll 4
    for (int d = 0; d < HD; d++) {
        ushort4 k0 = *(const ushort4*)(kb + (size_t)d * S + 4 * t);
        ushort4 k1 = *(const ushort4*)(kb + (size_t)d * S + 4 * t + 1024);
        float k0x = bu2f(k0.x), k0y = bu2f(k0.y), k0z = bu2f(k0.z), k0w = bu2f(k0.w);
        float k1x = bu2f(k1.x), k1y = bu2f(k1.y), k1z = bu2f(k1.z), k1w = bu2f(k1.w);
#pragma unroll
        for (int r = 0; r < 8; r++) {
            float qd = qs[r * 64 + d];
            acc[r][0] = fmaf(qd, k0x, acc[r][0]);
            acc[r][1] = fmaf(qd, k0y, acc[r][1]);
            acc[r][2] = fmaf(qd, k0z, acc[r][2]);
            acc[r][3] = fmaf(qd, k0w, acc[r][3]);
            acc[r][4] = fmaf(qd, k1x, acc[r][4]);
            acc[r][5] = fmaf(qd, k1y, acc[r][5]);
            acc[r][6] = fmaf(qd, k1z, acc[r][6]);
            acc[r][7] = fmaf(qd, k1w, acc[r][7]);
        }
    }
    const int4 mk0 = *(const int4*)(mask + 4 * t);
    const int4 mk1 = *(const int4*)(mask + 4 * t + 1024);
    __syncthreads();

    // scale = (1/sqrt(64)) * (1/2 from entmax) = 0.0625 ; masked -> -1e9/2
#pragma unroll
    for (int r = 0; r < 8; r++) {
        float4 w0, w1;
        w0.x = mk0.x ? acc[r][0] * 0.0625f : -5e8f;
        w0.y = mk0.y ? acc[r][1] * 0.0625f : -5e8f;
        w0.z = mk0.z ? acc[r][2] * 0.0625f : -5e8f;
        w0.w = mk0.w ? acc[r][3] * 0.0625f : -5e8f;
        w1.x = mk1.x ? acc[r][4] * 0.0625f : -5e8f;
        w1.y = mk1.y ? acc[r][5] * 0.0625f : -5e8f;
        w1.z = mk1.z ? acc[r][6] * 0.0625f : -5e8f;
        w1.w = mk1.w ? acc[r][7] * 0.0625f : -5e8f;
        *(float4*)&sc[r * 2048 + 4 * t]        = w0;
        *(float4*)&sc[r * 2048 + 4 * t + 1024] = w1;
    }
    __syncthreads();

    // entmax1.5 Newton: 32 lanes per row, row values cached in regs
    {
        const int lane = t & 63;
        const int r    = (t >> 6) * 2 + (lane >> 5);
        const int l32  = lane & 31;
        float xv[64];
#pragma unroll
        for (int j = 0; j < 64; j++) xv[j] = sc[r * 2048 + l32 + 32 * j];
        float mx = -1e30f;
#pragma unroll
        for (int j = 0; j < 64; j++) mx = fmaxf(mx, xv[j]);
#pragma unroll
        for (int off = 16; off >= 1; off >>= 1) mx = fmaxf(mx, __shfl_xor(mx, off, 32));
        float tau = mx - 1.0f;   // monotone Newton on convex decreasing g
        for (int it = 0; it < 12; it++) {
            float s1 = 0.f, s2 = 0.f;
#pragma unroll
            for (int j = 0; j < 64; j++) {
                float dp = fmaxf(xv[j] - tau, 0.f);
                s1 += dp; s2 = fmaf(dp, dp, s2);
            }
#pragma unroll
            for (int off = 16; off >= 1; off >>= 1) {
                s1 += __shfl_xor(s1, off, 32);
                s2 += __shfl_xor(s2, off, 32);
            }
            tau += (s2 - 1.0f) / (2.0f * s1);   // s1 >= 1 while g >= 1
        }
#pragma unroll
        for (int j = 0; j < 64; j++) {
            float dp = fmaxf(xv[j] - tau, 0.f);
            sc[r * 2048 + l32 + 32 * j] = dp * dp;   // P in place
        }
    }
    __syncthreads();

    // PV: thread (d = t&63, g = t>>6); P broadcast-read as float4
    {
        const int d = t & 63, g = t >> 6;
        float o[8] = {};
        const u16* vb = vbuf + (size_t)h * HD + d;
        for (int kq = 0; kq < 128; kq++) {
            int k = g * 512 + kq * 4;
            float v0 = bu2f(vb[(size_t)(k + 0) * D]);
            float v1 = bu2f(vb[(size_t)(k + 1) * D]);
            float v2 = bu2f(vb[(size_t)(k + 2) * D]);
            float v3 = bu2f(vb[(size_t)(k + 3) * D]);
#pragma unroll
            for (int r = 0; r < 8; r++) {
                float4 p = *(const float4*)&sc[r * 2048 + k];
                o[r] = fmaf(p.x, v0, o[r]);
                o[r] = fmaf(p.y, v1, o[r]);
                o[r] = fmaf(p.z, v2, o[r]);
                o[r] = fmaf(p.w, v3, o[r]);
            }
        }
        __syncthreads();
#pragma unroll
        for (int r = 0; r < 8; r++) sc[(g * 8 + r) * 64 + d] = o[r];
    }
    __syncthreads();
    for (int i = t; i < 512; i += 256) {
        int r = i >> 6, d = i & 63;
        float sum = sc[(0 * 8 + r) * 64 + d] + sc[(1 * 8 + r) * 64 + d]
                  + sc[(2 * 8 + r) * 64 + d] + sc[(3 * 8 + r) * 64 + d];
        att[(size_t)(q0 + r) * D + h * HD + d] = f2bu(sum);
    }
}

// ---------------- host side ---------------------------------------------------
extern "C" void kernel_launch(void* const* d_in, const int* in_sizes, int n_in,
                              void* d_out, int out_size, void* d_ws, size_t ws_size,
                              hipStream_t stream)
{
    const float* inp  = (const float*)d_in[0];
    const int*   mask = (const int*)d_in[1];
    const float* wq   = (const float*)d_in[2];
    const float* bq   = (const float*)d_in[3];
    const float* wk   = (const float*)d_in[4];
    const float* bk   = (const float*)d_in[5];
    const float* wv   = (const float*)d_in[6];
    const float* bv   = (const float*)d_in[7];
    const float* wo   = (const float*)d_in[8];
    const float* bo   = (const float*)d_in[9];
    const float* ln1a = (const float*)d_in[10];
    const float* ln1b = (const float*)d_in[11];
    const float* w1   = (const float*)d_in[12];
    const float* b1   = (const float*)d_in[13];
    const float* w2   = (const float*)d_in[14];
    const float* b2   = (const float*)d_in[15];
    const float* ln2a = (const float*)d_in[16];
    const float* ln2b = (const float*)d_in[17];

    const size_t MB = 1u << 20;
    char* w = (char*)d_ws;
    // 32 MB overlay (bf16 unless noted):
    //  [0,6):  wqb/wkb/wvb  -> w1b [0,8) after QKV -> w2b [0,8) after FFN1
    //  [8,12): x1 -> att -> x2
    //  [12,16): qbuf -> y (residual, bf16)
    //  [16,20): kTb   \
    //  [20,24): vbuf   > dead after attn -> hb [16,32)
    //  [24,26): wob   /  (dead after WO)
    u16* wqb = (u16*)(w + 0 * MB);
    u16* wkb = (u16*)(w + 2 * MB);
    u16* wvb = (u16*)(w + 4 * MB);
    u16* w1b = (u16*)(w + 0 * MB);
    u16* w2b = (u16*)(w + 0 * MB);
    u16* x1  = (u16*)(w + 8 * MB);
    u16* att = x1;
    u16* x2  = x1;
    u16* qb_ = (u16*)(w + 12 * MB);
    u16* yb  = (u16*)(w + 12 * MB);
    u16* kTb = (u16*)(w + 16 * MB);
    u16* vb_ = (u16*)(w + 20 * MB);
    u16* wob = (u16*)(w + 24 * MB);
    u16* hb  = (u16*)(w + 16 * MB);
    float* outF = (float*)d_out;

    // 0. weight conversions (QKV + WO up front)
    cvt_kernel<<<1024, 256, 0, stream>>>(wq, wqb, (D * D) / 4);
    cvt_kernel<<<1024, 256, 0, stream>>>(wk, wkb, (D * D) / 4);
    cvt_kernel<<<1024, 256, 0, stream>>>(wv, wvb, (D * D) / 4);
    cvt_kernel<<<1024, 256, 0, stream>>>(wo, wob, (D * D) / 4);
    // 1. LN1 -> bf16
    ln_kernel<float><<<S, 256, 0, stream>>>(inp, ln1a, ln1b, x1);
    // 2. Q, K(->transposed), V projections (bf16 out)
    gemm_mfma<1, false, 0><<<dim3(D / 128, S / 128), 256, 0, stream>>>(
        x1, wqb, bq, nullptr, qb_, S, D, D);
    gemm_mfma<3, false, 0><<<dim3(D / 128, S / 128), 256, 0, stream>>>(
        x1, wkb, bk, nullptr, kTb, S, D, D);
    gemm_mfma<1, false, 0><<<dim3(D / 128, S / 128), 256, 0, stream>>>(
        x1, wvb, bv, nullptr, vb_, S, D, D);
    // convert w1 now (wq/wk/wv slots dead after V)
    cvt_kernel<<<4096, 256, 0, stream>>>(w1, w1b, (DFF * D) / 4);
    // 3. fused entmax attention (writes att over x1 slot)
    attn_kernel<<<NH * (S / 8), 256, 0, stream>>>(qb_, kTb, vb_, mask, att);
    // 4. WO projection + residual(inp fp32) -> y bf16 (q slot dead)
    gemm_mfma<1, false, 1><<<dim3(D / 128, S / 128), 256, 0, stream>>>(
        att, wob, bo, inp, yb, S, D, D);
    // 5. LN2 -> x2 (att dead)
    ln_kernel<u16><<<S, 256, 0, stream>>>(yb, ln2a, ln2b, x2);
    // 6. FFN1 (+ReLU) -> hb bf16 (kT/v/wob dead)
    gemm_mfma<1, true, 0><<<dim3(DFF / 128, S / 128), 256, 0, stream>>>(
        x2, w1b, b1, nullptr, hb, S, DFF, D);
    // convert w2 (w1 slot dead)
    cvt_kernel<<<4096, 256, 0, stream>>>(w2, w2b, (DFF * D) / 4);
    // 7. FFN2 + residual(y bf16) -> fp32 out
    gemm_mfma<0, false, 2><<<dim3(D / 128, S / 128), 256, 0, stream>>>(
        hb, w2b, b2, yb, outF, S, D, DFF);
}

// Round 5
// 499.449 us; speedup vs baseline: 2.6226x; 1.5396x over previous
//
#include <hip/hip_runtime.h>
#include <hip/hip_bf16.h>

// Problem dims (fixed by setup_inputs)
#define S   2048
#define D   1024
#define DFF 4096
#define NH  16
#define HD  64

typedef unsigned short u16;
typedef unsigned int   u32;
typedef __attribute__((ext_vector_type(8))) short short8;   // 8 bf16 (4 VGPRs)
typedef __attribute__((ext_vector_type(4))) float floatx4;  // MFMA C/D

__device__ __forceinline__ float bu2f(u16 u) {
    union { u32 i; float f; } x; x.i = ((u32)u) << 16; return x.f;
}
__device__ __forceinline__ u16 f2bu(float f) {
    __hip_bfloat16 h = __float2bfloat16(f);
    return *(u16*)&h;
}
__device__ __forceinline__ float ldf(const float* p) { return *p; }
__device__ __forceinline__ float ldf(const u16* p)   { return bu2f(*p); }

// async global->LDS, 16B per lane, lands at ldsbase + lane*16
__device__ __forceinline__ void async16(const void* g, void* l) {
    __builtin_amdgcn_global_load_lds(
        (const __attribute__((address_space(1))) u32*)g,
        (__attribute__((address_space(3))) u32*)l, 16, 0, 0);
}

// ---------------- fp32 -> bf16 bulk convert (weights) ------------------------
__global__ __launch_bounds__(256)
void cvt_kernel(const float* __restrict__ in, u16* __restrict__ out, int n4)
{
    int i = blockIdx.x * 256 + threadIdx.x;
    if (i < n4) {
        float4 v = ((const float4*)in)[i];
        ushort4 s;
        s.x = f2bu(v.x); s.y = f2bu(v.y); s.z = f2bu(v.z); s.w = f2bu(v.w);
        ((ushort4*)out)[i] = s;
    }
}

// ---------------- LayerNorm: one block per row, D=1024, 256 threads ----------
template <typename T>
__global__ __launch_bounds__(256, 4)
void ln_kernel(const T* __restrict__ in, const float* __restrict__ ga,
               const float* __restrict__ gb, u16* __restrict__ out)
{
    const int row = blockIdx.x;
    const int t = threadIdx.x;
    const T* x = in + (size_t)row * D;
    float v[4];
    float s = 0.f, ss = 0.f;
#pragma unroll
    for (int j = 0; j < 4; j++) {
        float val = ldf(x + t + 256 * j);
        v[j] = val; s += val; ss = fmaf(val, val, ss);
    }
#pragma unroll
    for (int off = 32; off >= 1; off >>= 1) {
        s  += __shfl_down(s,  off, 64);
        ss += __shfl_down(ss, off, 64);
    }
    __shared__ float red[10];
    const int wave = t >> 6, lane = t & 63;
    if (lane == 0) { red[wave] = s; red[4 + wave] = ss; }
    __syncthreads();
    if (t == 0) {
        float S1 = red[0] + red[1] + red[2] + red[3];
        float S2 = red[4] + red[5] + red[6] + red[7];
        float mu = S1 / (float)D;
        float var = (S2 - (float)D * mu * mu) / (float)(D - 1);  // ddof=1
        float sig = sqrtf(fmaxf(var, 0.f)) + 1e-6f;              // eps on sigma
        red[8] = mu; red[9] = 1.f / sig;
    }
    __syncthreads();
    const float mu = red[8], rs = red[9];
#pragma unroll
    for (int j = 0; j < 4; j++) {
        int c = t + 256 * j;
        out[(size_t)row * D + c] = f2bu((v[j] - mu) * rs * ga[c] + gb[c]);
    }
}

// ======================= MFMA GEMM core (128x128 tile) =======================
// A,B bf16 row-major [M,K]/[N,K]. 256 thr = 4 waves (2x2 of 64x64), BK=32,
// global_load_lds width-16 staging, XOR-swizzled 16B LDS slots (2-way banks).
#define GEMM_CORE(A_, B_, K_)                                                   \
    __shared__ u16 As[128 * 32];                                                \
    __shared__ u16 Bs[128 * 32];                                                \
    const int t = threadIdx.x;                                                  \
    const int w = t >> 6, l = t & 63;                                           \
    const int m0 = blockIdx.y * 128, n0 = blockIdx.x * 128;                     \
    const int qk = l >> 4, col = l & 15;                                        \
    const int wm = (w & 1) * 64, wn = (w >> 1) * 64;                            \
    const int sr  = l >> 2;                                                     \
    const int sq  = l & 3;                                                      \
    const int row = w * 16 + sr;                                                \
    const int gq  = sq ^ ((row >> 1) & 3);                                      \
    const u16* Ap = A_ + (size_t)(m0 + row) * K_ + gq * 8;                      \
    const u16* Bp = B_ + (size_t)(n0 + row) * K_ + gq * 8;                      \
    u16* AsW = As + w * 16 * 32;                                                \
    u16* BsW = Bs + w * 16 * 32;                                                \
    const int mloc = wm + col, nloc = wn + col;                                 \
    const u16* aBase = As + mloc * 32 + (qk ^ ((mloc >> 1) & 3)) * 8;           \
    const u16* bBase = Bs + nloc * 32 + (qk ^ ((nloc >> 1) & 3)) * 8;           \
    floatx4 acc[4][4];                                                          \
    _Pragma("unroll")                                                           \
    for (int i = 0; i < 4; i++)                                                 \
        _Pragma("unroll")                                                       \
        for (int j = 0; j < 4; j++) acc[i][j] = (floatx4)0.f;                   \
    for (int k0 = 0; k0 < K_; k0 += 32) {                                       \
        __syncthreads();                                                        \
        async16(Ap,                  AsW);                                      \
        async16(Ap + (size_t)64 * K_, AsW + 64 * 32);                           \
        async16(Bp,                  BsW);                                      \
        async16(Bp + (size_t)64 * K_, BsW + 64 * 32);                           \
        Ap += 32; Bp += 32;                                                     \
        __syncthreads();                                                        \
        short8 a[4], b[4];                                                      \
        _Pragma("unroll")                                                       \
        for (int i = 0; i < 4; i++) a[i] = *(const short8*)(aBase + i * 16 * 32);\
        _Pragma("unroll")                                                       \
        for (int j = 0; j < 4; j++) b[j] = *(const short8*)(bBase + j * 16 * 32);\
        _Pragma("unroll")                                                       \
        for (int i = 0; i < 4; i++)                                             \
            _Pragma("unroll")                                                   \
            for (int j = 0; j < 4; j++)                                         \
                acc[i][j] = __builtin_amdgcn_mfma_f32_16x16x32_bf16(            \
                    a[i], b[j], acc[i][j], 0, 0, 0);                            \
    }
// epilogue C/D layout: col=lane&15, row=qk*4+reg  [m89/m91, round-4 verified]

// ---- generic single-output GEMM (+bias/relu/res), OMODE 0 f32 / 1 bf16 ------
template <int OMODE, bool RELU, int RES>
__global__ __launch_bounds__(256, 2)
void gemm_mfma(const u16* __restrict__ A, const u16* __restrict__ B,
               const float* __restrict__ bias, const void* __restrict__ res,
               void* __restrict__ Cout, int M, int N, int K)
{
    GEMM_CORE(A, B, K)
#pragma unroll
    for (int j = 0; j < 4; j++) {
        const int n = n0 + wn + j * 16 + col;
        const float bn = bias[n];
#pragma unroll
        for (int i = 0; i < 4; i++) {
#pragma unroll
            for (int r = 0; r < 4; r++) {
                const int m = m0 + wm + i * 16 + qk * 4 + r;
                float v = acc[i][j][r] + bn;
                if (RELU) v = fmaxf(v, 0.f);
                if (RES == 1) v += ((const float*)res)[(size_t)m * N + n];
                if (RES == 2) v += bu2f(((const u16*)res)[(size_t)m * N + n]);
                if (OMODE == 0) ((float*)Cout)[(size_t)m * N + n] = v;
                if (OMODE == 1) ((u16*)Cout)[(size_t)m * N + n] = f2bu(v);
            }
        }
    }
}

// ---- fused QKV GEMM: B = [wq;wk;wv] [3072,1024]; routes per 1024-segment ----
// seg 0 -> Q [S,D] bf16; seg 1 -> K [S,D] bf16; seg 2 -> V^T [D][S] bf16.
__global__ __launch_bounds__(256, 2)
void gemm_qkv(const u16* __restrict__ A, const u16* __restrict__ B,
              const float* __restrict__ bq, const float* __restrict__ bk,
              const float* __restrict__ bv, u16* __restrict__ outQ,
              u16* __restrict__ outK, u16* __restrict__ outVT)
{
    const int K = D;
    GEMM_CORE(A, B, K)
    const int seg   = n0 >> 10;
    const int nbase = n0 & 1023;
    const float* bs = (seg == 0) ? bq : (seg == 1) ? bk : bv;
    u16* outMN = (seg == 0) ? outQ : outK;
#pragma unroll
    for (int j = 0; j < 4; j++) {
        const int nl = nbase + wn + j * 16 + col;
        const float bn = bs[nl];
#pragma unroll
        for (int i = 0; i < 4; i++) {
#pragma unroll
            for (int r = 0; r < 4; r++) {
                const int m = m0 + wm + i * 16 + qk * 4 + r;
                float v = acc[i][j][r] + bn;
                if (seg < 2) outMN[(size_t)m * D + nl] = f2bu(v);
                else         outVT[(size_t)nl * S + m] = f2bu(v);
            }
        }
    }
}

// =================== MFMA fused sparse attention ============================
// Block: 16 q-rows of one head, 4 waves. Grid = NH * (S/16) = 2048.
// q,k: [S,D] bf16 ; vT: [D][S] bf16 (d-major) ; scores fp32 in regs;
// entmax1.5 tau via Newton (reg-resident, cross-wave LDS reduce);
// P -> LDS bf16 [16][2048] XOR-swizzled; PV via MFMA.
__global__ __launch_bounds__(256, 2)
void attn_mfma(const u16* __restrict__ qb, const u16* __restrict__ kb,
               const u16* __restrict__ vT, const int* __restrict__ mask,
               u16* __restrict__ att)
{
    __shared__ u16 Plds[16 * 2048];            // 64 KB; front doubles as red buf
    float* red = (float*)Plds;                 // [2][4 waves][16 rows][2] = 256 f
    const int h  = blockIdx.x >> 7;
    const int q0 = (blockIdx.x & 127) * 16;
    const int t  = threadIdx.x;
    const int w  = t >> 6, l = t & 63;
    const int lg = l >> 4, lc = l & 15;

    // Q a-frags: lane holds Q[q0+lc][h*64 + lg*8 + 32*half + j]
    const u16* qp = qb + (size_t)(q0 + lc) * D + h * HD + lg * 8;
    const short8 aq0 = *(const short8*)(qp);
    const short8 aq1 = *(const short8*)(qp + 32);

    // ---- QK^T: wave w owns keys [w*512, w*512+512), 32 tiles of 16 ----
    floatx4 acc[32];
#pragma unroll
    for (int tt = 0; tt < 32; tt++) acc[tt] = (floatx4)0.f;
    {
        const u16* kp0 = kb + (size_t)(w * 512 + lc) * D + h * HD + lg * 8;
#pragma unroll
        for (int tt = 0; tt < 32; tt++) {
            const u16* kp = kp0 + (size_t)tt * 16 * D;
            short8 b0 = *(const short8*)(kp);
            short8 b1 = *(const short8*)(kp + 32);
            acc[tt] = __builtin_amdgcn_mfma_f32_16x16x32_bf16(aq0, b0, acc[tt], 0, 0, 0);
            acc[tt] = __builtin_amdgcn_mfma_f32_16x16x32_bf16(aq1, b1, acc[tt], 0, 0, 0);
        }
    }

    // ---- mask + scale: scale = (1/sqrt(64))*(1/2) = 0.0625; masked -> -5e8 ----
#pragma unroll
    for (int tt = 0; tt < 32; tt++) {
        const int mk = mask[w * 512 + tt * 16 + lc];
#pragma unroll
        for (int r = 0; r < 4; r++)
            acc[tt][r] = mk ? acc[tt][r] * 0.0625f : -5e8f;
    }

    // ---- row max (rows lg*4+r), cross-lane then cross-wave ----
    float tau[4];
    {
        float mx[4] = {-3e38f, -3e38f, -3e38f, -3e38f};
#pragma unroll
        for (int tt = 0; tt < 32; tt++)
#pragma unroll
            for (int r = 0; r < 4; r++) mx[r] = fmaxf(mx[r], acc[tt][r]);
#pragma unroll
        for (int off = 1; off <= 8; off <<= 1)
#pragma unroll
            for (int r = 0; r < 4; r++)
                mx[r] = fmaxf(mx[r], __shfl_xor(mx[r], off, 64));
        if (lc == 0) {
#pragma unroll
            for (int r = 0; r < 4; r++)
                red[w * 32 + (lg * 4 + r) * 2] = mx[r];
        }
        __syncthreads();
#pragma unroll
        for (int r = 0; r < 4; r++) {
            const int rowi = (lg * 4 + r) * 2;
            float m = fmaxf(fmaxf(red[rowi], red[32 + rowi]),
                            fmaxf(red[64 + rowi], red[96 + rowi]));
            tau[r] = m - 1.0f;   // g(tau0) >= 1 -> monotone Newton
        }
    }

    // ---- Newton: 12 iters, 1 barrier each (double-buffered red) ----
    for (int it = 0; it < 12; it++) {
        const int p = ((it + 1) & 1) * 128;
        float s1[4] = {}, s2[4] = {};
#pragma unroll
        for (int tt = 0; tt < 32; tt++)
#pragma unroll
            for (int r = 0; r < 4; r++) {
                float dp = fmaxf(acc[tt][r] - tau[r], 0.f);
                s1[r] += dp; s2[r] = fmaf(dp, dp, s2[r]);
            }
#pragma unroll
        for (int off = 1; off <= 8; off <<= 1)
#pragma unroll
            for (int r = 0; r < 4; r++) {
                s1[r] += __shfl_xor(s1[r], off, 64);
                s2[r] += __shfl_xor(s2[r], off, 64);
            }
        if (lc == 0) {
#pragma unroll
            for (int r = 0; r < 4; r++) {
                const int base = p + w * 32 + (lg * 4 + r) * 2;
                red[base] = s1[r]; red[base + 1] = s2[r];
            }
        }
        __syncthreads();
#pragma unroll
        for (int r = 0; r < 4; r++) {
            const int rowi = (lg * 4 + r) * 2;
            float S1 = red[p + rowi] + red[p + 32 + rowi]
                     + red[p + 64 + rowi] + red[p + 96 + rowi];
            float S2 = red[p + 1 + rowi] + red[p + 33 + rowi]
                     + red[p + 65 + rowi] + red[p + 97 + rowi];
            tau[r] += (S2 - 1.0f) / (2.0f * S1);   // S1 >= 1 while g >= 1
        }
    }
    __syncthreads();   // all red reads done before P overwrites the area

    // ---- P = relu(x-tau)^2 -> LDS bf16, 16B-block XOR swizzle ----
    {
#pragma unroll
        for (int tt = 0; tt < 32; tt++) {
            const int key = w * 512 + tt * 16 + lc;
            const int blk = key >> 3;
#pragma unroll
            for (int r = 0; r < 4; r++) {
                const int rw = lg * 4 + r;
                float dp = fmaxf(acc[tt][r] - tau[r], 0.f);
                const int pb = (blk & ~7) | ((blk & 7) ^ (rw & 7));
                Plds[rw * 2048 + pb * 8 + (key & 7)] = f2bu(dp * dp);
            }
        }
    }
    __syncthreads();

    // ---- PV via MFMA: wave w -> d-tile [w*16, w*16+16), full 2048-contraction
    {
        floatx4 oacc = (floatx4)0.f;
        const u16* vp = vT + (size_t)(h * HD + w * 16 + lc) * S + lg * 8;
#pragma unroll 4
        for (int kt = 0; kt < 64; kt++) {
            const int blk = kt * 4 + lg;
            const int pb  = (blk & ~7) | ((blk & 7) ^ (lc & 7));
            short8 af = *(const short8*)&Plds[lc * 2048 + pb * 8];
            short8 bf = *(const short8*)(vp + kt * 32);
            oacc = __builtin_amdgcn_mfma_f32_16x16x32_bf16(af, bf, oacc, 0, 0, 0);
        }
#pragma unroll
        for (int r = 0; r < 4; r++)
            att[(size_t)(q0 + lg * 4 + r) * D + h * HD + w * 16 + lc] =
                f2bu(oacc[r]);
    }
}

// ---------------- host side ---------------------------------------------------
extern "C" void kernel_launch(void* const* d_in, const int* in_sizes, int n_in,
                              void* d_out, int out_size, void* d_ws, size_t ws_size,
                              hipStream_t stream)
{
    const float* inp  = (const float*)d_in[0];
    const int*   mask = (const int*)d_in[1];
    const float* wq   = (const float*)d_in[2];
    const float* bq   = (const float*)d_in[3];
    const float* wk   = (const float*)d_in[4];
    const float* bk   = (const float*)d_in[5];
    const float* wv   = (const float*)d_in[6];
    const float* bv   = (const float*)d_in[7];
    const float* wo   = (const float*)d_in[8];
    const float* bo   = (const float*)d_in[9];
    const float* ln1a = (const float*)d_in[10];
    const float* ln1b = (const float*)d_in[11];
    const float* w1   = (const float*)d_in[12];
    const float* b1   = (const float*)d_in[13];
    const float* w2   = (const float*)d_in[14];
    const float* b2   = (const float*)d_in[15];
    const float* ln2a = (const float*)d_in[16];
    const float* ln2b = (const float*)d_in[17];

    const size_t MB = 1u << 20;
    char* w = (char*)d_ws;
    // 32 MB overlay (bf16 unless noted):
    //  [0,8):  wqkvb(6MB) -> w1b (after QKV) -> w2b (after FFN1)
    //  [8,12): x1 -> att -> x2
    //  [12,16): qb_ -> yb
    //  [16,20): kb_  \
    //  [20,24): vTb   > dead after attn -> hb [16,32)
    //  [24,26): wob  /  (dead after WO, before FFN1 writes hb)
    u16* wqkvb = (u16*)(w + 0 * MB);
    u16* w1b   = (u16*)(w + 0 * MB);
    u16* w2b   = (u16*)(w + 0 * MB);
    u16* x1    = (u16*)(w + 8 * MB);
    u16* att   = x1;
    u16* x2    = x1;
    u16* qb_   = (u16*)(w + 12 * MB);
    u16* yb    = (u16*)(w + 12 * MB);
    u16* kb_   = (u16*)(w + 16 * MB);
    u16* vTb   = (u16*)(w + 20 * MB);
    u16* wob   = (u16*)(w + 24 * MB);
    u16* hb    = (u16*)(w + 16 * MB);
    float* outF = (float*)d_out;

    // 0. weight conversions: QKV concat + WO
    cvt_kernel<<<1024, 256, 0, stream>>>(wq, wqkvb,                 (D * D) / 4);
    cvt_kernel<<<1024, 256, 0, stream>>>(wk, wqkvb + 1024 * 1024,   (D * D) / 4);
    cvt_kernel<<<1024, 256, 0, stream>>>(wv, wqkvb + 2 * 1024 * 1024, (D * D) / 4);
    cvt_kernel<<<1024, 256, 0, stream>>>(wo, wob, (D * D) / 4);
    // 1. LN1 -> bf16
    ln_kernel<float><<<S, 256, 0, stream>>>(inp, ln1a, ln1b, x1);
    // 2. fused QKV projection: Q [S,D], K [S,D], V^T [D,S]
    gemm_qkv<<<dim3(3 * D / 128, S / 128), 256, 0, stream>>>(
        x1, wqkvb, bq, bk, bv, qb_, kb_, vTb);
    // 3. convert w1 (wqkvb dead)
    cvt_kernel<<<4096, 256, 0, stream>>>(w1, w1b, (DFF * D) / 4);
    // 4. MFMA fused entmax attention -> att (over x1 slot)
    attn_mfma<<<NH * (S / 16), 256, 0, stream>>>(qb_, kb_, vTb, mask, att);
    // 5. WO projection + residual(inp fp32) -> yb bf16 (q slot dead)
    gemm_mfma<1, false, 1><<<dim3(D / 128, S / 128), 256, 0, stream>>>(
        att, wob, bo, inp, yb, S, D, D);
    // 6. LN2 -> x2 (att dead)
    ln_kernel<u16><<<S, 256, 0, stream>>>(yb, ln2a, ln2b, x2);
    // 7. FFN1 (+ReLU) -> hb bf16 (kb_/vTb/wob dead)
    gemm_mfma<1, true, 0><<<dim3(DFF / 128, S / 128), 256, 0, stream>>>(
        x2, w1b, b1, nullptr, hb, S, DFF, D);
    // 8. convert w2 (w1b dead)
    cvt_kernel<<<4096, 256, 0, stream>>>(w2, w2b, (DFF * D) / 4);
    // 9. FFN2 + residual(yb bf16) -> fp32 out
    gemm_mfma<0, false, 2><<<dim3(D / 128, S / 128), 256, 0, stream>>>(
        hb, w2b, b2, yb, outF, S, D, DFF);
}